// Round 1
// baseline (134.057 us; speedup 1.0000x reference)
//
#include <hip/hip_runtime.h>
#include <math.h>

#define NB 2048
#define DEPTH 8

// ws layout (float offsets)
#define FTAB_OFF    0        // sponge fused cs: 8*5*256*8 = 81920 floats
#define BF01_OFF    81920    // bf stages 0-1: 256*3*2 float4 = 6144 floats
#define BFF_OFF     88064    // bf fused (2,3)..(10,11): 5*256*8 = 10240 floats
#define ACT4_OFF    98304    // act table: 2048 float4 = 8192 floats
#define PHYSA_OFF   106496   // int2 per (d,t): interleaved mem scatter addrs, 4096 ints
#define PHYSR_OFF   110592   // interleaved recall addrs [2048] int
#define PHYSO2_OFF  112640   // per-thread pre-gather absolute addrs [256*12] int
// total 115712 floats = 462848 bytes

// LDS map (floats): memb interleaved [0,4608); single exchange buf EX [4608,6656)
#define MB0 4608
#define EXB 4608

// wave-synchronous fence: single-wave workgroup, so a full lgkmcnt drain
// replaces __syncthreads (no s_barrier, and crucially NO vmcnt(0) drain --
// global table prefetches stay in flight across it)
#define WFENCE() asm volatile("s_waitcnt lgkmcnt(0)" ::: "memory")

// ---------------- single merged setup dispatch (unchanged) ----------------
__global__ void setup_kernel(const float* __restrict__ angles,
                             const float* __restrict__ bf_angles,
                             const float* __restrict__ act_bias,
                             const float* __restrict__ act_curv,
                             const int* __restrict__ recall_idx,
                             const int* __restrict__ out_mem_idx,
                             float* __restrict__ ws) {
    __shared__ int physL[4096];
    if (blockIdx.x < 200) {
        int id = blockIdx.x * 256 + threadIdx.x;
        if (id < 40960) {
            // sponge fused table: id = ((d*5+g)*256 + t)*4 + w ; quad a = 2*(t&127)+(t>>7)
            int w = id & 3, t = (id >> 2) & 255, dg = id >> 10;
            int d = dg / 5, g = dg - 5 * d;
            int a = 2 * (t & 127) + (t >> 7);
            int pair = (w == 0) ? a : (w == 1) ? (a + 256)
                     : (w == 2) ? (2 * a) : (2 * a + 1);
            int st = 2 * g + (w >> 1);
            float ang = angles[(d * 10 + st) * 512 + pair];
            float s, c; __sincosf(ang, &s, &c);
            ws[FTAB_OFF + 2 * id]     = c;
            ws[FTAB_OFF + 2 * id + 1] = s;
        } else if (id < 44032) {
            // BF01: e = (t*3+i)*4 + w ; a = t+256i
            int e = id - 40960;
            int w = e & 3; int ti = e >> 2;
            int t = ti / 3; int i = ti - 3 * t;
            int a = t + 256 * i;
            int pair = (w == 0) ? a : (w == 1) ? (a + 768)
                     : (w == 2) ? (2 * a) : (2 * a + 1);
            int stage = (w < 2) ? 0 : 1;
            float ang = bf_angles[stage * 1536 + pair];
            float s, c; __sincosf(ang, &s, &c);
            ws[BF01_OFF + 2 * e]     = c;
            ws[BF01_OFF + 2 * e + 1] = s;
        } else if (id < 49152) {
            // BFF: e = (f*256+t)*4 + w ; fused stages (2+2f, 3+2f)
            int e = id - 44032;
            int f = e >> 10; int rem = e & 1023; int t = rem >> 2; int w = rem & 3;
            int P;
            if (f == 0) P = 3 * t;
            else if (f < 4) { int k = 8 - 2 * f;
                              P = ((t >> (2 * f)) * (768 >> k)) + (t & ((256 >> k) - 1)); }
            else P = t;
            int pair = (w == 0) ? P : (w == 1) ? (P + 768)
                     : (w == 2) ? (2 * P) : (2 * P + 1);
            int stage = (w < 2) ? (2 + 2 * f) : (3 + 2 * f);
            float ang = bf_angles[stage * 1536 + pair];
            float s, c; __sincosf(ang, &s, &c);
            ws[BFF_OFF + 2 * e]     = c;
            ws[BFF_OFF + 2 * e + 1] = s;
        } else if (id < 51200) {
            int ida = id - 49152;              // d*256 + k
            float cu = act_curv[ida];
            float c  = 0.5f * (cu + sqrtf(cu * cu + 1.0f));
            ((float4*)(ws + ACT4_OFF))[ida] =
                make_float4(act_bias[ida], c, 1.0f / c, 0.0f);
        }
    } else {
        // phys block: compacted mem slot allocation (2304 phys slots)
        int tid = threadIdx.x;
        for (int e = tid; e < 4096; e += 256) {
            int v = e, p;
            for (;;) {
                int d = v >> 9, j = v & 511;
                if (d == 0)  { p = j; break; }
                if (j < 256) { p = 256 + d * 256 + j; break; }
                v = recall_idx[(d - 1) * 256 + (j - 256)];
            }
            physL[e] = p;
        }
        __syncthreads();
        int* pa = (int*)(ws + PHYSA_OFF);
        for (int e = tid; e < 2048; e += 256) {
            int d = e >> 8, t = e & 255;
            int a = 2 * (t & 127) + (t >> 7);
            pa[2 * e]     = 2 * physL[d * 512 + 2 * a];       // interleaved addr
            pa[2 * e + 1] = 2 * physL[d * 512 + 2 * a + 1];
        }
        int* pr = (int*)(ws + PHYSR_OFF);
        for (int e = tid; e < 2048; e += 256)
            pr[e] = 2 * physL[recall_idx[e]];                 // interleaved addr
        int* po = (int*)(ws + PHYSO2_OFF);
        for (int e = tid; e < 3072; e += 256) {
            int tt = e / 12; int r = e - 12 * tt; int i = r >> 2; int k = r & 3;
            int a = tt + 256 * i;
            int tl2 = a >> 1, th2 = a & 1;
            int pos = tl2 + 1536 * th2 + 384 * k;
            po[e] = (pos < 2048) ? 2 * physL[out_mem_idx[pos]]
                                 : MB0 + 2 * (pos - 2048);    // absolute lds addr
        }
    }
}

__device__ __forceinline__ float actf(float x, float c, float ic) {
    const float is2 = 0.70710678118654752f;
    float tt = 0.78539816339744831f * ic;
    float y0 = is2 * ic;
    float y1 = (is2 - 1.0f) * ic;
    float mid = ic * (is2 - __cosf(0.78539816339744831f + c * x));
    return x > tt ? (y0 + (x - tt)) : (x < -tt ? y1 : mid);
}

// ---------------- main kernel: 1 WAVE per block, 2 rows, wave-synchronous LDS ----
// Each lane does the work of 4 old threads t = lane + 64*q (q unrolled), so every
// LDS instruction's per-wave address pattern -- and thus bank behavior -- is
// identical to the old kernel's per-wave patterns. All setup tables reused as-is.
// Single exchange buffer (in-order per-wave DS + lgkmcnt fences at both
// boundaries make RAW and WAR safe without double-buffering or s_barrier).
__launch_bounds__(64, 2)
__global__ void sponge_kernel(const float* __restrict__ X,
                              const float* __restrict__ scales,
                              const float* __restrict__ ws,
                              float* __restrict__ out) {
    __shared__ float L[6656];            // 26624 B -> 6 blocks/CU LDS cap
    const int lane = threadIdx.x;
    const int rowA = blockIdx.x * 2;

    const float4* ftab   = (const float4*)(ws + FTAB_OFF);
    const float4* bf01   = (const float4*)(ws + BF01_OFF);
    const float4* bff    = (const float4*)(ws + BFF_OFF);
    const float4* act4   = (const float4*)(ws + ACT4_OFF);
    const int2*   physA  = (const int2*)(ws + PHYSA_OFF);
    const int*    physr  = (const int*)(ws + PHYSR_OFF);
    const int*    physo2 = (const int*)(ws + PHYSO2_OFF);

    float hA[4][4], hB[4][4];            // holdings: 4 virtual threads x 4 quads
    {
        const float* Xr0 = X + (size_t)rowA * 1024;
        const float* Xr1 = Xr0 + 1024;
#pragma unroll
        for (int q = 0; q < 4; ++q) {
            int tq = lane + 64 * q;
            int b  = (tq & 127) + (tq >> 7) * 512;
#pragma unroll
            for (int k = 0; k < 4; ++k) {
                float s = scales[b + 128 * k];
                hA[q][k] = Xr0[b + 128 * k] * s;
                hB[q][k] = Xr1[b + 128 * k] * s;
            }
        }
    }

#define DQUAD(cA, cB, i0, i1, i2, i3, F0, F1, F2, F3)                    \
    { float g0 =  (cA).x * (i0) + (cA).y * (i2);                         \
      float g2 = -(cA).y * (i0) + (cA).x * (i2);                         \
      float g1 =  (cA).z * (i1) + (cA).w * (i3);                         \
      float g3 = -(cA).w * (i1) + (cA).z * (i3);                         \
      F0 =  (cB).x * g0 + (cB).y * g1;                                   \
      F2 = -(cB).y * g0 + (cB).x * g1;                                   \
      F1 =  (cB).z * g2 + (cB).w * g3;                                   \
      F3 = -(cB).w * g2 + (cB).z * g3; }

    float4 cs[4][2];                     // current group's fused cos/sin per q
    int fb = 0;                          // ftab base (float4 units), +512/group
#define LOADC()                                                          \
    { _Pragma("unroll")                                                  \
      for (int q = 0; q < 4; ++q) {                                      \
          int tq = lane + 64 * q;                                        \
          cs[q][0] = ftab[fb + 2 * tq];                                  \
          cs[q][1] = ftab[fb + 2 * tq + 1];                              \
      } fb += 512; }

    LOADC();                             // group (0,0)

#pragma unroll 1
    for (int d = 0; d < DEPTH; ++d) {
        // prefetch this depth's act/recall/scatter metadata (consumed at g==4,
        // ~4 groups of latency cover; fences never drain vmcnt)
        float4 av[2][4]; int pr2[2][2]; int2 pmv[4];
#pragma unroll
        for (int q = 0; q < 2; ++q) {
            int k0 = (lane + 64 * q) >> 1;
#pragma unroll
            for (int j = 0; j < 4; ++j) av[q][j] = act4[d * 256 + k0 + 64 * j];
            int u = lane + 64 * q;
            pr2[q][0] = physr[d * 256 + u];
            pr2[q][1] = physr[d * 256 + u + 128];
        }
#pragma unroll
        for (int q = 0; q < 4; ++q) pmv[q] = physA[d * 256 + lane + 64 * q];

        for (int g = 0; g < 4; ++g) {
#pragma unroll
            for (int q = 0; q < 4; ++q) {
                int tq = lane + 64 * q;
                int tl = tq & 127, th = tq >> 7;
                int WI = 2 * (2 * (tl & 15) + 32 * th + 64 * (tl >> 4));
                float fA0, fA1, fA2, fA3, fB0, fB1, fB2, fB3;
                DQUAD(cs[q][0], cs[q][1], hA[q][0], hA[q][1], hA[q][2], hA[q][3],
                      fA0, fA1, fA2, fA3);
                DQUAD(cs[q][0], cs[q][1], hB[q][0], hB[q][1], hB[q][2], hB[q][3],
                      fB0, fB1, fB2, fB3);
                *(float4*)(L + EXB + WI)        = make_float4(fA0, fB0, fA1, fB1);
                *(float4*)(L + EXB + WI + 1024) = make_float4(fA2, fB2, fA3, fB3);
            }
            WFENCE();                    // writes visible (RAW)
            LOADC();                     // next group's coeffs fly over the reads
#pragma unroll
            for (int q = 0; q < 4; ++q) {
                int tq = lane + 64 * q;
                int tl = tq & 127, th = tq >> 7;
                int RI = 2 * ((tl & 1) + 2 * ((tl >> 2) & 15) + 32 * ((tl >> 1) & 1)
                             + 64 * (tl >> 6) + 512 * th);
                float2 e0 = *(const float2*)(L + EXB + RI);
                float2 e1 = *(const float2*)(L + EXB + RI + 256);
                float2 e2 = *(const float2*)(L + EXB + RI + 512);
                float2 e3 = *(const float2*)(L + EXB + RI + 768);
                hA[q][0] = e0.x; hB[q][0] = e0.y; hA[q][1] = e1.x; hB[q][1] = e1.y;
                hA[q][2] = e2.x; hB[q][2] = e2.y; hA[q][3] = e3.x; hB[q][3] = e3.y;
            }
            WFENCE();                    // reads drained (WAR vs next writes)
        }

        // ---- g==4: mem scatter + keep + activation + recall ----
#pragma unroll
        for (int q = 0; q < 4; ++q) {
            int tq = lane + 64 * q;
            int tl = tq & 127, th = tq >> 7;
            int aq = 2 * tl + th;
            float fA0, fA1, fA2, fA3, fB0, fB1, fB2, fB3;
            DQUAD(cs[q][0], cs[q][1], hA[q][0], hA[q][1], hA[q][2], hA[q][3],
                  fA0, fA1, fA2, fA3);
            DQUAD(cs[q][0], cs[q][1], hB[q][0], hB[q][1], hB[q][2], hB[q][3],
                  fB0, fB1, fB2, fB3);
            *(float2*)(L + pmv[q].x) = make_float2(fA0, fB0);   // memb scatter
            *(float2*)(L + pmv[q].y) = make_float2(fA1, fB1);
            *(float4*)(L + EXB + 4 * aq) = make_float4(fA2, fB2, fA3, fB3); // Z
        }
        WFENCE();
        if (d < DEPTH - 1) LOADC();      // next depth's (d+1,0) coeffs
        {
            const float* Z = L + EXB;
#pragma unroll
            for (int q = 0; q < 2; ++q) {           // virtual t<128: activation
                int tq = lane + 64 * q;
                int k0 = tq >> 1;
                float sgn = (tq & 1) ? -1.0f : 1.0f;
                float2 z0 = *(const float2*)(Z + 2 * k0);
                float2 z1 = *(const float2*)(Z + 2 * k0 + 128);
                float2 z2 = *(const float2*)(Z + 2 * k0 + 256);
                float2 z3 = *(const float2*)(Z + 2 * k0 + 384);
                hA[q][0] = actf(sgn * (z0.x + av[q][0].x), av[q][0].y, av[q][0].z);
                hB[q][0] = actf(sgn * (z0.y + av[q][0].x), av[q][0].y, av[q][0].z);
                hA[q][1] = actf(sgn * (z1.x + av[q][1].x), av[q][1].y, av[q][1].z);
                hB[q][1] = actf(sgn * (z1.y + av[q][1].x), av[q][1].y, av[q][1].z);
                hA[q][2] = actf(sgn * (z2.x + av[q][2].x), av[q][2].y, av[q][2].z);
                hB[q][2] = actf(sgn * (z2.y + av[q][2].x), av[q][2].y, av[q][2].z);
                hA[q][3] = actf(sgn * (z3.x + av[q][3].x), av[q][3].y, av[q][3].z);
                hB[q][3] = actf(sgn * (z3.y + av[q][3].x), av[q][3].y, av[q][3].z);
            }
#pragma unroll
            for (int q = 0; q < 2; ++q) {           // virtual t>=128: keep+recall
                int u = lane + 64 * q;
                float2 k0v = *(const float2*)(Z + 512 + 2 * u);
                float2 k1v = *(const float2*)(Z + 768 + 2 * u);
                float2 rc0 = *(const float2*)(L + pr2[q][0]);
                float2 rc1 = *(const float2*)(L + pr2[q][1]);
                hA[2 + q][0] = k0v.x; hB[2 + q][0] = k0v.y;
                hA[2 + q][1] = k1v.x; hB[2 + q][1] = k1v.y;
                hA[2 + q][2] = rc0.x; hB[2 + q][2] = rc0.y;
                hA[2 + q][3] = rc1.x; hB[2 + q][3] = rc1.y;
            }
        }
        WFENCE();                        // Z/recall reads drained before next writes
    }

    // ---- stage sponge into natural interleaved layout at EXB ----
    // prefetch gather addresses first so they issue before the fence
    int4 pga[4][3];
#pragma unroll
    for (int q = 0; q < 4; ++q) {
        const int4* pgp = (const int4*)(physo2 + (lane + 64 * q) * 12);
#pragma unroll
        for (int j = 0; j < 3; ++j) pga[q][j] = pgp[j];
    }
#pragma unroll
    for (int q = 0; q < 4; ++q) {
        int tq = lane + 64 * q;
        int b  = (tq & 127) + (tq >> 7) * 512;
        *(float2*)(L + EXB + 2 * b)       = make_float2(hA[q][0], hB[q][0]);
        *(float2*)(L + EXB + 2 * b + 256) = make_float2(hA[q][1], hB[q][1]);
        *(float2*)(L + EXB + 2 * b + 512) = make_float2(hA[q][2], hB[q][2]);
        *(float2*)(L + EXB + 2 * b + 768) = make_float2(hA[q][3], hB[q][3]);
    }
    WFENCE();

    // ---- gather pre: 12 b64 loads per virtual thread (absolute addrs) ----
    float2 w[4][12];
#pragma unroll
    for (int q = 0; q < 4; ++q) {
        int4 pg = pga[q][0];
        w[q][0] = *(const float2*)(L + pg.x); w[q][1] = *(const float2*)(L + pg.y);
        w[q][2] = *(const float2*)(L + pg.z); w[q][3] = *(const float2*)(L + pg.w);
        pg = pga[q][1];
        w[q][4] = *(const float2*)(L + pg.x); w[q][5] = *(const float2*)(L + pg.y);
        w[q][6] = *(const float2*)(L + pg.z); w[q][7] = *(const float2*)(L + pg.w);
        pg = pga[q][2];
        w[q][8]  = *(const float2*)(L + pg.x); w[q][9]  = *(const float2*)(L + pg.y);
        w[q][10] = *(const float2*)(L + pg.z); w[q][11] = *(const float2*)(L + pg.w);
    }
    WFENCE();                            // all gathers in regs before overwrite

    // ---- fused stages (0,1); final buffer = interleaved [0,6144) ----
#pragma unroll
    for (int q = 0; q < 4; ++q) {
        int tq = lane + 64 * q;
#pragma unroll
        for (int i = 0; i < 3; ++i) {
            float4 c01 = bf01[(tq * 3 + i) * 2];
            float4 c23 = bf01[(tq * 3 + i) * 2 + 1];
            float yA0, yA1, yA2, yA3, yB0, yB1, yB2, yB3;
            DQUAD(c01, c23, w[q][4*i].x, w[q][4*i+1].x, w[q][4*i+2].x, w[q][4*i+3].x,
                  yA0, yA1, yA2, yA3);
            DQUAD(c01, c23, w[q][4*i].y, w[q][4*i+1].y, w[q][4*i+2].y, w[q][4*i+3].y,
                  yB0, yB1, yB2, yB3);
            *(float4*)(L + 4 * tq + 1024 * i)        = make_float4(yA0, yB0, yA1, yB1);
            *(float4*)(L + 4 * tq + 1024 * i + 3072) = make_float4(yA2, yB2, yA3, yB3);
        }
    }
    WFENCE();

    // ---- fused pruned double-stages (2,3) (4,5) (6,7) (8,9) ----
#pragma unroll
    for (int f = 0; f < 4; ++f) {
        float2 x1p[4], x1r[4], x2p[4], x2r[4];
        float4 cS[4], cT[4];
        int Pq[4];
#pragma unroll
        for (int q = 0; q < 4; ++q) {
            int tq = lane + 64 * q;
            cS[q] = bff[(f * 256 + tq) * 2];      // issued before fence: free overlap
            cT[q] = bff[(f * 256 + tq) * 2 + 1];
            int P;
            if (f == 0) P = 3 * tq;
            else { const int k = 8 - 2 * f;
                   P = ((tq >> (2 * f)) * (768 >> k)) + (tq & ((256 >> k) - 1)); }
            Pq[q] = P;
            int base = 2 * ((P >> 1) + (P & 1) * 1536);
            x1p[q] = *(const float2*)(L + base);
            x1r[q] = *(const float2*)(L + base + 768);
            x2p[q] = *(const float2*)(L + base + 1536);
            x2r[q] = *(const float2*)(L + base + 2304);
        }
        WFENCE();                        // all reads done before in-place writes
#pragma unroll
        for (int q = 0; q < 4; ++q) {
            float4 csS = cS[q], csT = cT[q];
            float o1P =  csS.x * x1p[q].x + csS.y * x2p[q].x;
            float o2P = -csS.y * x1p[q].x + csS.x * x2p[q].x;
            float o1Q =  csS.z * x1r[q].x + csS.w * x2r[q].x;
            float o2Q = -csS.w * x1r[q].x + csS.z * x2r[q].x;
            float yA0 =  csT.x * o1P + csT.y * o1Q;
            float yA2 = -csT.y * o1P + csT.x * o1Q;
            float yA1 =  csT.z * o2P + csT.w * o2Q;
            float yA3 = -csT.w * o2P + csT.z * o2Q;
            o1P =  csS.x * x1p[q].y + csS.y * x2p[q].y;
            o2P = -csS.y * x1p[q].y + csS.x * x2p[q].y;
            o1Q =  csS.z * x1r[q].y + csS.w * x2r[q].y;
            o2Q = -csS.w * x1r[q].y + csS.z * x2r[q].y;
            float yB0 =  csT.x * o1P + csT.y * o1Q;
            float yB2 = -csT.y * o1P + csT.x * o1Q;
            float yB1 =  csT.z * o2P + csT.w * o2Q;
            float yB3 = -csT.w * o2P + csT.z * o2Q;
            *(float4*)(L + 4 * Pq[q])        = make_float4(yA0, yB0, yA1, yB1);
            *(float4*)(L + 4 * Pq[q] + 3072) = make_float4(yA2, yB2, yA3, yB3);
        }
        WFENCE();
    }

    // ---- fused (10,11) + output store, both rows ----
#pragma unroll
    for (int q = 0; q < 4; ++q) {
        int tq = lane + 64 * q;
        int base = 2 * ((tq >> 1) + (tq & 1) * 1536);
        float4 csS = bff[(4 * 256 + tq) * 2];
        float4 csT = bff[(4 * 256 + tq) * 2 + 1];
        float2 x1p = *(const float2*)(L + base);
        float2 x1r = *(const float2*)(L + base + 768);
        float2 x2p = *(const float2*)(L + base + 1536);
        float2 x2r = *(const float2*)(L + base + 2304);
        float o1P =  csS.x * x1p.x + csS.y * x2p.x;
        float o2P = -csS.y * x1p.x + csS.x * x2p.x;
        float o1Q =  csS.z * x1r.x + csS.w * x2r.x;
        float o2Q = -csS.w * x1r.x + csS.z * x2r.x;
        *(float2*)(out + (size_t)rowA * 512 + 2 * tq) =
            make_float2(csT.x * o1P + csT.y * o1Q, csT.z * o2P + csT.w * o2Q);
        o1P =  csS.x * x1p.y + csS.y * x2p.y;
        o2P = -csS.y * x1p.y + csS.x * x2p.y;
        o1Q =  csS.z * x1r.y + csS.w * x2r.y;
        o2Q = -csS.w * x1r.y + csS.z * x2r.y;
        *(float2*)(out + (size_t)(rowA + 1) * 512 + 2 * tq) =
            make_float2(csT.x * o1P + csT.y * o1Q, csT.z * o2P + csT.w * o2Q);
    }
#undef DQUAD
#undef LOADC
}

extern "C" void kernel_launch(void* const* d_in, const int* in_sizes, int n_in,
                              void* d_out, int out_size, void* d_ws, size_t ws_size,
                              hipStream_t stream) {
    const float* X          = (const float*)d_in[0];
    const float* scales     = (const float*)d_in[1];
    const float* angles     = (const float*)d_in[2];
    const float* act_bias   = (const float*)d_in[3];
    // d_in[4] act_activation — unused by the reference
    const float* act_curv   = (const float*)d_in[5];
    const float* bf_angles  = (const float*)d_in[6];
    // d_in[7] shuffle_perm — structural perfect shuffle, hardcoded
    const int*   recall_idx  = (const int*)d_in[8];
    const int*   out_mem_idx = (const int*)d_in[9];
    // d_in[10] bf_perm — structural perfect shuffle, hardcoded

    float* ws = (float*)d_ws;   // 462848 bytes used

    setup_kernel<<<201, 256, 0, stream>>>(angles, bf_angles, act_bias, act_curv,
                                          recall_idx, out_mem_idx, ws);
    sponge_kernel<<<NB / 2, 64, 0, stream>>>(X, scales, ws, (float*)d_out);
}

// Round 2
// 112.583 us; speedup vs baseline: 1.1907x; 1.1907x over previous
//
#include <hip/hip_runtime.h>
#include <math.h>

#define NB 2048
#define DEPTH 8

// ws layout (float offsets)
#define FTAB_OFF    0        // sponge fused cs: 8*5*256*8 = 81920 floats
#define BF01_OFF    81920    // bf stages 0-1: 256*3*2 float4 = 6144 floats
#define BFF_OFF     88064    // bf fused (2,3)..(10,11): 5*256*8 = 10240 floats
#define ACT4_OFF    98304    // act table: 2048 float4 = 8192 floats
#define PHYSA_OFF   106496   // int2 per (d,t): interleaved mem scatter addrs, 4096 ints
#define PHYSR_OFF   110592   // interleaved recall addrs [2048] int
#define PHYSO2_OFF  112640   // per-thread pre-gather absolute addrs [256*12] int
// total 115712 floats = 462848 bytes

// LDS map (floats): memb interleaved [0,4608); exch buf0 [4608,6656); buf1 [6656,8704)
#define MB0 4608
#define MB1 6656

// soft barrier: drain LDS ops only, then barrier. Avoids __syncthreads'
// vmcnt(0) drain so global prefetches (coeffs/act/physr/gather addrs)
// stay in flight across workgroup barriers. All producer->consumer deps
// at these barriers are DS ops, so lgkmcnt(0) is sufficient.
#define SBAR() asm volatile("s_waitcnt lgkmcnt(0)\n\ts_barrier" ::: "memory")

// ---------------- single merged setup dispatch ----------------
__global__ void setup_kernel(const float* __restrict__ angles,
                             const float* __restrict__ bf_angles,
                             const float* __restrict__ act_bias,
                             const float* __restrict__ act_curv,
                             const int* __restrict__ recall_idx,
                             const int* __restrict__ out_mem_idx,
                             float* __restrict__ ws) {
    __shared__ int physL[4096];
    __shared__ int rcl[2048];
    __shared__ int oml[2048];
    if (blockIdx.x < 200) {
        int id = blockIdx.x * 256 + threadIdx.x;
        if (id < 40960) {
            // sponge fused table: id = ((d*5+g)*256 + t)*4 + w ; quad a = 2*(t&127)+(t>>7)
            int w = id & 3, t = (id >> 2) & 255, dg = id >> 10;
            int d = dg / 5, g = dg - 5 * d;
            int a = 2 * (t & 127) + (t >> 7);
            int pair = (w == 0) ? a : (w == 1) ? (a + 256)
                     : (w == 2) ? (2 * a) : (2 * a + 1);
            int st = 2 * g + (w >> 1);
            float ang = angles[(d * 10 + st) * 512 + pair];
            float s, c; __sincosf(ang, &s, &c);
            ws[FTAB_OFF + 2 * id]     = c;
            ws[FTAB_OFF + 2 * id + 1] = s;
        } else if (id < 44032) {
            // BF01: e = (t*3+i)*4 + w ; a = t+256i
            int e = id - 40960;
            int w = e & 3; int ti = e >> 2;
            int t = ti / 3; int i = ti - 3 * t;
            int a = t + 256 * i;
            int pair = (w == 0) ? a : (w == 1) ? (a + 768)
                     : (w == 2) ? (2 * a) : (2 * a + 1);
            int stage = (w < 2) ? 0 : 1;
            float ang = bf_angles[stage * 1536 + pair];
            float s, c; __sincosf(ang, &s, &c);
            ws[BF01_OFF + 2 * e]     = c;
            ws[BF01_OFF + 2 * e + 1] = s;
        } else if (id < 49152) {
            // BFF: e = (f*256+t)*4 + w ; fused stages (2+2f, 3+2f)
            int e = id - 44032;
            int f = e >> 10; int rem = e & 1023; int t = rem >> 2; int w = rem & 3;
            int P;
            if (f == 0) P = 3 * t;
            else if (f < 4) { int k = 8 - 2 * f;
                              P = ((t >> (2 * f)) * (768 >> k)) + (t & ((256 >> k) - 1)); }
            else P = t;
            int pair = (w == 0) ? P : (w == 1) ? (P + 768)
                     : (w == 2) ? (2 * P) : (2 * P + 1);
            int stage = (w < 2) ? (2 + 2 * f) : (3 + 2 * f);
            float ang = bf_angles[stage * 1536 + pair];
            float s, c; __sincosf(ang, &s, &c);
            ws[BFF_OFF + 2 * e]     = c;
            ws[BFF_OFF + 2 * e + 1] = s;
        } else if (id < 51200) {
            int ida = id - 49152;              // d*256 + k
            float cu = act_curv[ida];
            float c  = 0.5f * (cu + sqrtf(cu * cu + 1.0f));
            ((float4*)(ws + ACT4_OFF))[ida] =
                make_float4(act_bias[ida], c, 1.0f / c, 0.0f);
        }
    } else {
        // phys block: compacted mem slot allocation (2304 phys slots).
        // Depth-ascending DP in LDS replaces the per-element dependent
        // global pointer-chase (recall targets at depth d reference only
        // indices < 512*d, so resolving d = 0..7 in order needs no chase).
        int tid = threadIdx.x;
        for (int e = tid; e < 2048; e += 256) rcl[e] = recall_idx[e];
        for (int e = tid; e < 2048; e += 256) oml[e] = out_mem_idx[e];
        for (int e = tid; e < 512; e += 256) physL[e] = e;   // d = 0: p = j
        __syncthreads();
        for (int d = 1; d < 8; ++d) {
            for (int j = tid; j < 512; j += 256) {
                int p;
                if (j < 256) p = 256 + d * 256 + j;
                else          p = physL[rcl[(d - 1) * 256 + (j - 256)]];
                physL[512 * d + j] = p;
            }
            __syncthreads();
        }
        int* pa = (int*)(ws + PHYSA_OFF);
        for (int e = tid; e < 2048; e += 256) {
            int d = e >> 8, t = e & 255;
            int a = 2 * (t & 127) + (t >> 7);
            pa[2 * e]     = 2 * physL[d * 512 + 2 * a];       // interleaved addr
            pa[2 * e + 1] = 2 * physL[d * 512 + 2 * a + 1];
        }
        int* pr = (int*)(ws + PHYSR_OFF);
        for (int e = tid; e < 2048; e += 256)
            pr[e] = 2 * physL[rcl[e]];                        // interleaved addr
        int* po = (int*)(ws + PHYSO2_OFF);
        for (int e = tid; e < 3072; e += 256) {
            int tt = e / 12; int r = e - 12 * tt; int i = r >> 2; int k = r & 3;
            int a = tt + 256 * i;
            int tl2 = a >> 1, th2 = a & 1;
            int pos = tl2 + 1536 * th2 + 384 * k;
            po[e] = (pos < 2048) ? 2 * physL[oml[pos]]
                                 : MB0 + 2 * (pos - 2048);    // absolute lds addr
        }
    }
}

__device__ __forceinline__ float actf(float x, float c, float ic) {
    const float is2 = 0.70710678118654752f;
    float tt = 0.78539816339744831f * ic;
    float y0 = is2 * ic;
    float y1 = (is2 - 1.0f) * ic;
    float mid = ic * (is2 - __cosf(0.78539816339744831f + c * x));
    return x > tt ? (y0 + (x - tt)) : (x < -tt ? y1 : mid);
}

// ---------------- main kernel: 2 rows per block, row-interleaved LDS ---------------
__launch_bounds__(256, 4)
__global__ void sponge_kernel(const float* __restrict__ X,
                              const float* __restrict__ scales,
                              const float* __restrict__ ws,
                              float* __restrict__ out) {
    __shared__ float L[8704];            // 34816 B -> 4 blocks/CU
    const int t = threadIdx.x;
    const int rowA = blockIdx.x * 2;

    const float4* bf01  = (const float4*)(ws + BF01_OFF);
    const float4* bff   = (const float4*)(ws + BFF_OFF);
    const float4* act4  = (const float4*)(ws + ACT4_OFF);
    const int2* physA  = (const int2*)(ws + PHYSA_OFF);
    const int*  physr  = (const int*)(ws + PHYSR_OFF);
    const int*  physo2 = (const int*)(ws + PHYSO2_OFF);

    const int tl = t & 127, th = t >> 7;
    const int b  = tl + th * 512;        // holdings {b+128m}; quad a = 2tl+th
    const int a  = 2 * tl + th;
    // bit-permutation layout A: A0=p0, A1..A4=p2..p5, A5=p1, A6..A9=p6..p9
    const int Wb = 2 * (tl & 15) + 32 * th + 64 * (tl >> 4);    // A(2a)
    const int Rb = (tl & 1) + 2 * ((tl >> 2) & 15) + 32 * ((tl >> 1) & 1)
                 + 64 * (tl >> 6) + 512 * th;                   // A(b)
    const int WI = 2 * Wb;               // b128 write base (interleaved)
    const int RI = 2 * Rb;               // b64 read base, +256m
    const int u  = t - 128;

    float hA0, hA1, hA2, hA3, hB0, hB1, hB2, hB3;
    {
        const float* Xr0 = X + (size_t)rowA * 1024;
        const float* Xr1 = Xr0 + 1024;
        float s0 = scales[b],       s1 = scales[b + 128];
        float s2 = scales[b + 256], s3 = scales[b + 384];
        hA0 = Xr0[b] * s0; hA1 = Xr0[b + 128] * s1;
        hA2 = Xr0[b + 256] * s2; hA3 = Xr0[b + 384] * s3;
        hB0 = Xr1[b] * s0; hB1 = Xr1[b + 128] * s1;
        hB2 = Xr1[b + 256] * s2; hB3 = Xr1[b + 384] * s3;
    }

    int woff = MB0, roff = MB1;
    const float4* ft = (const float4*)(ws + FTAB_OFF) + 2 * t;
    float4 csA = ft[0], csB = ft[1];     // group (0,0); pipeline one ahead below

#define DQUAD(cA, cB, i0, i1, i2, i3, F0, F1, F2, F3)                    \
    { float g0 =  (cA).x * (i0) + (cA).y * (i2);                         \
      float g2 = -(cA).y * (i0) + (cA).x * (i2);                         \
      float g1 =  (cA).z * (i1) + (cA).w * (i3);                         \
      float g3 = -(cA).w * (i1) + (cA).z * (i3);                         \
      F0 =  (cB).x * g0 + (cB).y * g1;                                   \
      F2 = -(cB).y * g0 + (cB).x * g1;                                   \
      F1 =  (cB).z * g2 + (cB).w * g3;                                   \
      F3 = -(cB).w * g2 + (cB).z * g3; }

    for (int d = 0; d < DEPTH; ++d) {
        for (int g = 0; g < 5; ++g) {
            float fA0, fA1, fA2, fA3, fB0, fB1, fB2, fB3;
            DQUAD(csA, csB, hA0, hA1, hA2, hA3, fA0, fA1, fA2, fA3);
            DQUAD(csA, csB, hB0, hB1, hB2, hB3, fB0, fB1, fB2, fB3);
            if (g < 4) {
                // logical {2a,2a+1} both rows -> contiguous b128; {2a+512,2a+513} at +1024
                *(float4*)(L + woff + WI)        = make_float4(fA0, fB0, fA1, fB1);
                *(float4*)(L + woff + WI + 1024) = make_float4(fA2, fB2, fA3, fB3);
                { int tmp = woff; woff = roff; roff = tmp; }
                ft += 512;                       // prefetch next group's coeffs:
                float4 nA = ft[0], nB = ft[1];   // in flight across the barrier
                SBAR();
                float2 e0 = *(const float2*)(L + roff + RI);
                float2 e1 = *(const float2*)(L + roff + RI + 256);
                float2 e2 = *(const float2*)(L + roff + RI + 512);
                float2 e3 = *(const float2*)(L + roff + RI + 768);
                hA0 = e0.x; hB0 = e0.y; hA1 = e1.x; hB1 = e1.y;
                hA2 = e2.x; hB2 = e2.y; hA3 = e3.x; hB3 = e3.y;
                csA = nA; csB = nB;
            } else {
                // mem half (2a,2a+1): b64 scatter into interleaved memb
                int2 pm = physA[d * 256 + t];
                *(float2*)(L + pm.x) = make_float2(fA0, fB0);
                *(float2*)(L + pm.y) = make_float2(fA1, fB1);
                // sponge half -> natural interleaved Z at zpos {2a, 2a+1}: b128 at 4a
                *(float4*)(L + woff + 4 * a) = make_float4(fA2, fB2, fA3, fB3);
                { int tmp = woff; woff = roff; roff = tmp; }
                ft += 512;                       // next depth's (d+1,0) coeffs
                float4 nA = ft[0], nB = ft[1];   // (last iter reads into BF01 tab: benign)
                // prefetch before barrier (wave-aligned split)
                int r0 = 0, r1 = 0;
                float4 a0, a1, a2, a3;
                if (t < 128) {
                    int k0 = t >> 1;
                    a0 = act4[d * 256 + k0];
                    a1 = act4[d * 256 + k0 + 64];
                    a2 = act4[d * 256 + k0 + 128];
                    a3 = act4[d * 256 + k0 + 192];
                } else {
                    r0 = physr[d * 256 + u];
                    r1 = physr[d * 256 + u + 128];
                }
                SBAR();                  // Z + mem scatter visible (LDS only)
                const float* Z = L + roff;
                if (t < 128) {
                    int k0 = t >> 1;
                    float sgn = (t & 1) ? -1.0f : 1.0f;
                    float2 z0 = *(const float2*)(Z + 2 * k0);
                    float2 z1 = *(const float2*)(Z + 2 * k0 + 128);
                    float2 z2 = *(const float2*)(Z + 2 * k0 + 256);
                    float2 z3 = *(const float2*)(Z + 2 * k0 + 384);
                    hA0 = actf(sgn * (z0.x + a0.x), a0.y, a0.z);
                    hB0 = actf(sgn * (z0.y + a0.x), a0.y, a0.z);
                    hA1 = actf(sgn * (z1.x + a1.x), a1.y, a1.z);
                    hB1 = actf(sgn * (z1.y + a1.x), a1.y, a1.z);
                    hA2 = actf(sgn * (z2.x + a2.x), a2.y, a2.z);
                    hB2 = actf(sgn * (z2.y + a2.x), a2.y, a2.z);
                    hA3 = actf(sgn * (z3.x + a3.x), a3.y, a3.z);
                    hB3 = actf(sgn * (z3.y + a3.x), a3.y, a3.z);
                } else {
                    // keep: zpos {256+u, 384+u}
                    float2 k0v = *(const float2*)(Z + 512 + 2 * u);
                    float2 k1v = *(const float2*)(Z + 768 + 2 * u);
                    float2 rc0 = *(const float2*)(L + r0);
                    float2 rc1 = *(const float2*)(L + r1);
                    hA0 = k0v.x; hB0 = k0v.y;
                    hA1 = k1v.x; hB1 = k1v.y;
                    hA2 = rc0.x; hB2 = rc0.y;
                    hA3 = rc1.x; hB3 = rc1.y;
                }
                csA = nA; csB = nB;
            }
        }
    }

    // ---- prefetch gather addrs, then stage sponge into natural layout at MB0 ----
    int4 pg0, pg1, pg2;
    {
        const int4* pgp = (const int4*)(physo2 + t * 12);
        pg0 = pgp[0]; pg1 = pgp[1]; pg2 = pgp[2];
    }
    *(float2*)(L + MB0 + 2 * b)       = make_float2(hA0, hB0);
    *(float2*)(L + MB0 + 2 * b + 256) = make_float2(hA1, hB1);
    *(float2*)(L + MB0 + 2 * b + 512) = make_float2(hA2, hB2);
    *(float2*)(L + MB0 + 2 * b + 768) = make_float2(hA3, hB3);
    SBAR();

    // ---- gather pre: 12 b64 loads (absolute addrs), both rows at once ----
    float2 w0, w1, w2, w3, w4, w5, w6, w7, w8, w9, w10, w11;
    w0 = *(const float2*)(L + pg0.x); w1 = *(const float2*)(L + pg0.y);
    w2 = *(const float2*)(L + pg0.z); w3 = *(const float2*)(L + pg0.w);
    w4 = *(const float2*)(L + pg1.x); w5 = *(const float2*)(L + pg1.y);
    w6 = *(const float2*)(L + pg1.z); w7 = *(const float2*)(L + pg1.w);
    w8 = *(const float2*)(L + pg2.x); w9 = *(const float2*)(L + pg2.y);
    w10 = *(const float2*)(L + pg2.z); w11 = *(const float2*)(L + pg2.w);
    SBAR();                              // all reads done before overwrite

    // ---- fused stages (0,1) in registers; final buffer = interleaved [0,6144) ----
#define BF01_STEP(i, q0, q1, q2, q3)                                                \
    {                                                                               \
        float4 c01 = bf01[(t * 3 + (i)) * 2];                                       \
        float4 c23 = bf01[(t * 3 + (i)) * 2 + 1];                                   \
        float yA0, yA1, yA2, yA3, yB0, yB1, yB2, yB3;                               \
        DQUAD(c01, c23, q0.x, q1.x, q2.x, q3.x, yA0, yA1, yA2, yA3);                \
        DQUAD(c01, c23, q0.y, q1.y, q2.y, q3.y, yB0, yB1, yB2, yB3);                \
        *(float4*)(L + 4 * t + 1024 * (i))        = make_float4(yA0, yB0, yA1, yB1);\
        *(float4*)(L + 4 * t + 1024 * (i) + 3072) = make_float4(yA2, yB2, yA3, yB3);\
    }
    BF01_STEP(0, w0, w1, w2, w3)
    BF01_STEP(1, w4, w5, w6, w7)
    BF01_STEP(2, w8, w9, w10, w11)
#undef BF01_STEP
    SBAR();

    // ---- fused pruned double-stages (2,3) (4,5) (6,7) (8,9) ----
#pragma unroll
    for (int f = 0; f < 4; ++f) {
        int P;
        if (f == 0) P = 3 * t;
        else { const int k = 8 - 2 * f;
               P = ((t >> (2 * f)) * (768 >> k)) + (t & ((256 >> k) - 1)); }
        int base = 2 * ((P >> 1) + (P & 1) * 1536);
        float4 csS = bff[(f * 256 + t) * 2];
        float4 csT = bff[(f * 256 + t) * 2 + 1];
        float2 x1p = *(const float2*)(L + base);
        float2 x1q = *(const float2*)(L + base + 768);
        float2 x2p = *(const float2*)(L + base + 1536);
        float2 x2q = *(const float2*)(L + base + 2304);
        float o1P =  csS.x * x1p.x + csS.y * x2p.x;
        float o2P = -csS.y * x1p.x + csS.x * x2p.x;
        float o1Q =  csS.z * x1q.x + csS.w * x2q.x;
        float o2Q = -csS.w * x1q.x + csS.z * x2q.x;
        float yA0 =  csT.x * o1P + csT.y * o1Q;
        float yA2 = -csT.y * o1P + csT.x * o1Q;
        float yA1 =  csT.z * o2P + csT.w * o2Q;
        float yA3 = -csT.w * o2P + csT.z * o2Q;
        o1P =  csS.x * x1p.y + csS.y * x2p.y;
        o2P = -csS.y * x1p.y + csS.x * x2p.y;
        o1Q =  csS.z * x1q.y + csS.w * x2q.y;
        o2Q = -csS.w * x1q.y + csS.z * x2q.y;
        float yB0 =  csT.x * o1P + csT.y * o1Q;
        float yB2 = -csT.y * o1P + csT.x * o1Q;
        float yB1 =  csT.z * o2P + csT.w * o2Q;
        float yB3 = -csT.w * o2P + csT.z * o2Q;
        SBAR();
        *(float4*)(L + 4 * P)        = make_float4(yA0, yB0, yA1, yB1);
        *(float4*)(L + 4 * P + 3072) = make_float4(yA2, yB2, yA3, yB3);
        SBAR();
    }

    // ---- fused (10,11) + output store, both rows ----
    {
        int base = 2 * ((t >> 1) + (t & 1) * 1536);
        float4 csS = bff[(4 * 256 + t) * 2];
        float4 csT = bff[(4 * 256 + t) * 2 + 1];
        float2 x1p = *(const float2*)(L + base);
        float2 x1q = *(const float2*)(L + base + 768);
        float2 x2p = *(const float2*)(L + base + 1536);
        float2 x2q = *(const float2*)(L + base + 2304);
        float o1P =  csS.x * x1p.x + csS.y * x2p.x;
        float o2P = -csS.y * x1p.x + csS.x * x2p.x;
        float o1Q =  csS.z * x1q.x + csS.w * x2q.x;
        float o2Q = -csS.w * x1q.x + csS.z * x2q.x;
        *(float2*)(out + (size_t)rowA * 512 + 2 * t) =
            make_float2(csT.x * o1P + csT.y * o1Q, csT.z * o2P + csT.w * o2Q);
        o1P =  csS.x * x1p.y + csS.y * x2p.y;
        o2P = -csS.y * x1p.y + csS.x * x2p.y;
        o1Q =  csS.z * x1q.y + csS.w * x2q.y;
        o2Q = -csS.w * x1q.y + csS.z * x2q.y;
        *(float2*)(out + (size_t)(rowA + 1) * 512 + 2 * t) =
            make_float2(csT.x * o1P + csT.y * o1Q, csT.z * o2P + csT.w * o2Q);
    }
#undef DQUAD
}

extern "C" void kernel_launch(void* const* d_in, const int* in_sizes, int n_in,
                              void* d_out, int out_size, void* d_ws, size_t ws_size,
                              hipStream_t stream) {
    const float* X          = (const float*)d_in[0];
    const float* scales     = (const float*)d_in[1];
    const float* angles     = (const float*)d_in[2];
    const float* act_bias   = (const float*)d_in[3];
    // d_in[4] act_activation — unused by the reference
    const float* act_curv   = (const float*)d_in[5];
    const float* bf_angles  = (const float*)d_in[6];
    // d_in[7] shuffle_perm — structural perfect shuffle, hardcoded
    const int*   recall_idx  = (const int*)d_in[8];
    const int*   out_mem_idx = (const int*)d_in[9];
    // d_in[10] bf_perm — structural perfect shuffle, hardcoded

    float* ws = (float*)d_ws;   // 462848 bytes used

    setup_kernel<<<201, 256, 0, stream>>>(angles, bf_angles, act_bias, act_curv,
                                          recall_idx, out_mem_idx, ws);
    sponge_kernel<<<NB / 2, 256, 0, stream>>>(X, scales, ws, (float*)d_out);
}